// Round 1
// baseline (1154.295 us; speedup 1.0000x reference)
//
#include <hip/hip_runtime.h>

// ChainMessagePassing: out[n] = sum over edges with dst==n of x[src], over two edge lists.
// x: [N=100000, 64] fp32; indices: [2, E=3200000] (src row 0, dst row 1), int64 or int32.
//
// R5: full per-node CSR build (100K bins) replaces R4's bucket sort + per-bucket LDS
// counting sort. Rationale from R4 counters: gather was occupancy/latency-limited
// (Occ 54%, VALUBusy 9%, 3.38 TB/s fetch != any hard ceiling) and carried a redundant
// in-LDS sort (~4 DS-ops/edge + 2nd global pass over packed); scatter ran 391 blocks
// (1.5/CU) with 2-pass LDS atomics. New pipeline:
//   hist (global atomics, per-node) -> 2-kernel scan -> 1-pass scatter (global cursor
//   atomics, 2048 blocks) -> pure gather (contiguous runs, unroll-8, 24 waves/CU).

static constexpr int D = 64;
static constexpr int Q = 16;          // float4 quads per row
static constexpr int NPB = 32;        // nodes per gather block
static constexpr int SB = 256;        // scan blocks (must equal scan block dim)

// ---- index dtype sniffer: int64 nonneg <2^31 has all-zero odd dwords ----
__global__ void detect_idx_dtype(const int* __restrict__ w, int* __restrict__ flag) {
    int tid = threadIdx.x;  // one wave
    int v = w[2 * tid + 1];
    unsigned long long m = __ballot(v != 0);
    if (tid == 0) *flag = (m == 0ULL) ? 1 : 0;
}

__device__ __forceinline__ int load_idx(const void* idx, long long i, int is64) {
    return is64 ? (int)((const long long*)idx)[i] : ((const int*)idx)[i];
}

// ---- phase 1: per-node degree histogram, direct global atomics ----
// 6.4M atomics over 100K addresses (~64/address) spread across all L2 channels.
__global__ __launch_bounds__(256) void hist_kernel(
        const void* __restrict__ up, const void* __restrict__ down,
        int* __restrict__ counts, const int* __restrict__ flag, int E) {
    const int is64 = *flag;
    const long long total = 2LL * E;
    const long long stride = (long long)gridDim.x * blockDim.x;
    for (long long e = (long long)blockIdx.x * blockDim.x + threadIdx.x;
         e < total; e += stride) {
        const void* idx = up; long long ee = e;
        if (ee >= E) { idx = down; ee -= E; }
        int dst = load_idx(idx, E + ee, is64);
        atomicAdd(&counts[dst], 1);
    }
}

// ---- phase 2a: per-block partial sums over counts ----
__global__ __launch_bounds__(256) void scan_partials_kernel(
        const int* __restrict__ counts, int* __restrict__ partials,
        int N, int cpt) {
    __shared__ int red[256];
    const int blk = blockIdx.x, tid = threadIdx.x;
    const long long base = (long long)(blk * 256 + tid) * cpt;
    int s = 0;
    for (int k = 0; k < cpt; k++) {
        long long i = base + k;
        if (i < N) s += counts[i];
    }
    red[tid] = s;
    __syncthreads();
    for (int off = 128; off > 0; off >>= 1) {
        if (tid < off) red[tid] += red[tid + off];
        __syncthreads();
    }
    if (tid == 0) partials[blk] = red[0];
}

// ---- phase 2b: apply — per-block base from partials, block scan, write offsets+cursors ----
__global__ __launch_bounds__(256) void scan_apply_kernel(
        const int* __restrict__ counts, const int* __restrict__ partials,
        int* __restrict__ offsets, int* __restrict__ cursors,
        int N, int cpt, int total) {
    __shared__ int sh[256];
    const int blk = blockIdx.x, tid = threadIdx.x;
    // base = sum of partials[0..blk)
    sh[tid] = (tid < blk) ? partials[tid] : 0;   // SB == 256 == blockDim
    __syncthreads();
    for (int off = 128; off > 0; off >>= 1) {
        if (tid < off) sh[tid] += sh[tid + off];
        __syncthreads();
    }
    const int bbase = sh[0];
    __syncthreads();
    // per-thread sum of its contiguous cpt counts
    const long long base = (long long)(blk * 256 + tid) * cpt;
    int s = 0;
    for (int k = 0; k < cpt; k++) {
        long long i = base + k;
        if (i < N) s += counts[i];
    }
    sh[tid] = s;
    __syncthreads();
    // Hillis-Steele inclusive scan over 256 thread sums
    for (int off = 1; off < 256; off <<= 1) {
        int t = (tid >= off) ? sh[tid - off] : 0;
        __syncthreads();
        sh[tid] += t;
        __syncthreads();
    }
    int run = bbase + ((tid == 0) ? 0 : sh[tid - 1]);
    for (int k = 0; k < cpt; k++) {
        long long i = base + k;
        if (i < N) {
            int c = counts[i];
            offsets[i] = run;
            cursors[i] = run;
            run += c;
        }
    }
    if (blk == 0 && tid == 0) offsets[N] = total;
}

// ---- phase 3: single-pass scatter of src into per-node runs ----
__global__ __launch_bounds__(256) void scatter_kernel(
        const void* __restrict__ up, const void* __restrict__ down,
        int* __restrict__ cursors, int* __restrict__ srcbuf,
        const int* __restrict__ flag, int E) {
    const int is64 = *flag;
    const long long total = 2LL * E;
    const long long stride = (long long)gridDim.x * blockDim.x;
    for (long long e = (long long)blockIdx.x * blockDim.x + threadIdx.x;
         e < total; e += stride) {
        const void* idx = up; long long ee = e;
        if (ee >= E) { idx = down; ee -= E; }
        int src = load_idx(idx, ee, is64);
        int dst = load_idx(idx, E + ee, is64);
        int pos = atomicAdd(&cursors[dst], 1);
        __builtin_nontemporal_store(src, &srcbuf[pos]);
    }
}

// ---- phase 4: pure gather. 16 lanes per node (lane q owns float4 quad q),
// 2 nodes per 16-lane group, 32 nodes per 256-thread block. Runs are contiguous
// in srcbuf; 8 row-gathers in flight per group. ----
__global__ __launch_bounds__(256, 6) void gather_kernel(
        const float* __restrict__ x, const int* __restrict__ offsets,
        const int* __restrict__ srcs, float* __restrict__ out, int N) {
    const int tid = threadIdx.x;
    const int g = tid >> 4;   // group 0..15
    const int q = tid & 15;   // quad within row
    const float* xq = x + q * 4;

    #pragma unroll
    for (int j = 0; j < 2; j++) {
        const int node = blockIdx.x * NPB + 2 * g + j;
        if (node < N) {
            const int rb = offsets[node];
            const int re = offsets[node + 1];
            float4 acc = make_float4(0.f, 0.f, 0.f, 0.f);
            int e = rb;
            for (; e + 8 <= re; e += 8) {  // 8 row-gathers in flight
                const int s0 = __builtin_nontemporal_load(srcs + e + 0);
                const int s1 = __builtin_nontemporal_load(srcs + e + 1);
                const int s2 = __builtin_nontemporal_load(srcs + e + 2);
                const int s3 = __builtin_nontemporal_load(srcs + e + 3);
                const int s4 = __builtin_nontemporal_load(srcs + e + 4);
                const int s5 = __builtin_nontemporal_load(srcs + e + 5);
                const int s6 = __builtin_nontemporal_load(srcs + e + 6);
                const int s7 = __builtin_nontemporal_load(srcs + e + 7);
                const float4 v0 = *(const float4*)(xq + (long long)s0 * D);
                const float4 v1 = *(const float4*)(xq + (long long)s1 * D);
                const float4 v2 = *(const float4*)(xq + (long long)s2 * D);
                const float4 v3 = *(const float4*)(xq + (long long)s3 * D);
                const float4 v4 = *(const float4*)(xq + (long long)s4 * D);
                const float4 v5 = *(const float4*)(xq + (long long)s5 * D);
                const float4 v6 = *(const float4*)(xq + (long long)s6 * D);
                const float4 v7 = *(const float4*)(xq + (long long)s7 * D);
                acc.x += ((v0.x + v1.x) + (v2.x + v3.x)) + ((v4.x + v5.x) + (v6.x + v7.x));
                acc.y += ((v0.y + v1.y) + (v2.y + v3.y)) + ((v4.y + v5.y) + (v6.y + v7.y));
                acc.z += ((v0.z + v1.z) + (v2.z + v3.z)) + ((v4.z + v5.z) + (v6.z + v7.z));
                acc.w += ((v0.w + v1.w) + (v2.w + v3.w)) + ((v4.w + v5.w) + (v6.w + v7.w));
            }
            for (; e < re; e++) {
                const int s = __builtin_nontemporal_load(srcs + e);
                const float4 v = *(const float4*)(xq + (long long)s * D);
                acc.x += v.x; acc.y += v.y; acc.z += v.z; acc.w += v.w;
            }
            *(float4*)(out + (long long)node * D + q * 4) = acc;
        }
    }
}

// ---- fallback: direct fp32 atomics (R1), needs no workspace ----
__global__ __launch_bounds__(256) void scatter_add_kernel(
        const float* __restrict__ x, const void* __restrict__ up_idx,
        const void* __restrict__ down_idx, float* __restrict__ out,
        const int* __restrict__ dtype_flag, int num_edges) {
    const int is64 = *dtype_flag;
    const long long total = 2LL * num_edges * Q;
    const long long stride = (long long)gridDim.x * blockDim.x;
    for (long long t = (long long)blockIdx.x * blockDim.x + threadIdx.x;
         t < total; t += stride) {
        const int quad = (int)(t & (Q - 1));
        long long eg = t >> 4;
        const void* idx = up_idx;
        if (eg >= num_edges) { idx = down_idx; eg -= num_edges; }
        int src = load_idx(idx, eg, is64);
        int dst = load_idx(idx, num_edges + eg, is64);
        const float4 v = *(const float4*)(x + (long long)src * D + quad * 4);
        float* o = out + (long long)dst * D + quad * 4;
        unsafeAtomicAdd(o + 0, v.x);
        unsafeAtomicAdd(o + 1, v.y);
        unsafeAtomicAdd(o + 2, v.z);
        unsafeAtomicAdd(o + 3, v.w);
    }
}

extern "C" void kernel_launch(void* const* d_in, const int* in_sizes, int n_in,
                              void* d_out, int out_size, void* d_ws, size_t ws_size,
                              hipStream_t stream) {
    const float* x = (const float*)d_in[0];
    const void* up_idx = d_in[1];
    const void* down_idx = d_in[2];
    float* out = (float*)d_out;

    const int E = in_sizes[1] / 2;   // [2, E]
    const int N = out_size / D;      // [N, 64]
    const long long Etot = 2LL * E;

    // ws layout (ints): flag(64) | counts[N] | offsets[N+16] | cursors[N] | partials[320] | srcbuf[2E]
    int* ws_i = (int*)d_ws;
    int* flag = ws_i;
    int* counts = ws_i + 64;
    int* offsets = counts + N;
    int* cursors = offsets + N + 16;
    int* partials = cursors + N;
    int* srcbuf = partials + 320;
    const size_t ws_need = ((size_t)64 + 3LL * N + 16 + 320 + (size_t)Etot) * 4 + 64;

    detect_idx_dtype<<<1, 64, 0, stream>>>((const int*)up_idx, flag);

    if (ws_size >= ws_need && Etot < (1LL << 31) && N >= 1) {
        hipMemsetAsync(counts, 0, (size_t)N * sizeof(int), stream);
        hist_kernel<<<2048, 256, 0, stream>>>(up_idx, down_idx, counts, flag, E);
        const int cpt = (N + SB * 256 - 1) / (SB * 256);
        scan_partials_kernel<<<SB, 256, 0, stream>>>(counts, partials, N, cpt);
        scan_apply_kernel<<<SB, 256, 0, stream>>>(counts, partials, offsets, cursors,
                                                  N, cpt, (int)Etot);
        scatter_kernel<<<2048, 256, 0, stream>>>(up_idx, down_idx, cursors, srcbuf,
                                                 flag, E);
        gather_kernel<<<(N + NPB - 1) / NPB, 256, 0, stream>>>(x, offsets, srcbuf, out, N);
    } else {
        hipMemsetAsync(d_out, 0, (size_t)out_size * sizeof(float), stream);
        scatter_add_kernel<<<8192, 256, 0, stream>>>(x, up_idx, down_idx, out, flag, E);
    }
}